// Round 7
// baseline (209.776 us; speedup 1.0000x reference)
//
#include <hip/hip_runtime.h>

#define L2E 1.4426950408889634f

typedef _Float16 f16x8 __attribute__((ext_vector_type(8)));
typedef _Float16 f16x4 __attribute__((ext_vector_type(4)));
typedef float f32x4 __attribute__((ext_vector_type(4)));

__device__ __forceinline__ float sig_fast(float x) {
    return __builtin_amdgcn_rcpf(1.0f + __builtin_amdgcn_exp2f(-L2E * x));
}
__device__ __forceinline__ float tanh_fast(float x) {
    return 1.0f - 2.0f * __builtin_amdgcn_rcpf(1.0f + __builtin_amdgcn_exp2f(2.0f * L2E * x));
}
__device__ __forceinline__ float expnr_fast(float x) {  // exp(-relu(x))
    return __builtin_amdgcn_exp2f(-L2E * fmaxf(x, 0.0f));
}
// Orders LDS only; global loads/stores stay in flight across the barrier.
// volatile asm -> never merged/eliminated by the compiler (unlike
// back-to-back __syncthreads, which risk dedup and barrier-pairing slip).
__device__ __forceinline__ void barrier_lds_only() {
    __asm__ volatile("s_waitcnt lgkmcnt(0)\n\ts_barrier" ::: "memory");
}

struct F8 { float v[8]; };
__device__ __forceinline__ F8 ld8(const float* p) {
    F8 r;
    float4 a = *(const float4*)p, b = *(const float4*)(p + 4);
    r.v[0]=a.x; r.v[1]=a.y; r.v[2]=a.z; r.v[3]=a.w;
    r.v[4]=b.x; r.v[5]=b.y; r.v[6]=b.z; r.v[7]=b.w;
    return r;
}
__device__ __forceinline__ f16x8 cvt8(F8 a) {
    f16x8 r;
#pragma unroll
    for (int q = 0; q < 8; ++q) r[q] = (_Float16)a.v[q];
    return r;
}
__device__ __forceinline__ f16x8 cvt8s(F8 a, F8 b) {
    f16x8 r;
#pragma unroll
    for (int q = 0; q < 8; ++q) r[q] = (_Float16)(a.v[q] + b.v[q]);
    return r;
}

// 256 blocks x 4 batch rows, 768 threads = 12 waves (3 waves/SIMD):
//   waves 0-7 (consumers): serial GRU recurrence, h-part GEMM (K=128).
//     Wave w owns 16 hidden cols: 16 MFMAs + ONE gate triple per step.
//   waves 8-11 (producers): x/m-part GEMM (h-independent) one granule
//     (4 steps) ahead into an 8-slot LDS ring + tail projection + mu.
// Preamble: explicit barrier BETWEEN prodStage(0) and prodMMA(0) — the
// cross-wave Astage race here was the R6 NaN (stale LDS can be f16 NaN).
__global__ __launch_bounds__(768, 3) void grud_kernel(
    const float* __restrict__ tp_pred, const float* __restrict__ X,
    const float* __restrict__ tp_true, const float* __restrict__ mask,
    const float* __restrict__ Wh_dec, const float* __restrict__ bh_dec,
    const float* __restrict__ Wx_dec, const float* __restrict__ bx_dec,
    const float* __restrict__ W_ih, const float* __restrict__ W_hh,
    const float* __restrict__ b_ih, const float* __restrict__ b_hh,
    const float* __restrict__ Wp, const float* __restrict__ bp,
    float* __restrict__ out)
{
    constexpr int SR = 136;  // A-tile row stride (halfs): 128 + 8 pad
    __shared__ alignas(16) _Float16 ring[8 * 2048];  // [slot][c*16+b*4+{r,z,n,pad}] 32KB
    __shared__ alignas(16) _Float16 V[2][16 * SR];   // h A-tiles (rows {0,4,8,12} live)
    __shared__ alignas(16) _Float16 Astage[16 * SR]; // producer x_in/m A-tile
    __shared__ float dt_lds[480];                    // [t][b]
    __shared__ float mu_l[4][64];
    __shared__ float wxl[64], bxl[64];

    const int tid  = threadIdx.x;
    const int w    = tid >> 6, l = tid & 63, quad = l >> 4, lm = l & 15;
    const int b0   = blockIdx.x * 4;

    // zero V (invalid tile rows must stay 0 forever); covers both buffers
    for (int i = tid; i < 16 * SR; i += 768) ((unsigned*)V)[i] = 0;

    // dt
    if (tid < 480) {
        int t = tid >> 2, q = tid & 3, b = b0 + q;
        float v = 0.0f;
        if (t) {
            float cur = (t < 96) ? tp_true[b * 96 + t] : tp_pred[b * 24 + t - 96];
            float prv = (t - 1 < 96) ? tp_true[b * 96 + t - 1] : tp_pred[b * 24 + t - 97];
            v = cur - prv;
        }
        dt_lds[tid] = v;
    }
    if (tid < 64) { wxl[tid] = Wx_dec[tid * 65]; bxl[tid] = bx_dec[tid]; }

    if (w >= 8) {
        // ===================== PRODUCER WAVES (8..11) =====================
        const int pw   = w - 8;          // 0..3
        const int ptid = tid - 512;      // 0..255
        const int c0   = 32 * pw + lm, c1 = c0 + 16;

        // mu for batch pw (lane l -> feature l)
        {
            const float* xr = X    + ((size_t)(b0 + pw) * 96) * 64 + l;
            const float* mr = mask + ((size_t)(b0 + pw) * 96) * 64 + l;
            float a = 0.0f, c = 0.0f;
#pragma unroll 4
            for (int t = 0; t < 96; ++t) {
                float x = xr[t * 64], m = mr[t * 64];
                a += x * (1.0f - m); c += 1.0f - m;
            }
            mu_l[pw][l] = a / (c + 24.0f);  // cnt = sum(1-m) + 24 >= 24, no clip
        }

        // x/m-part B-frags: k<64 -> W_ih[:, :64]; k>=64 -> W_ih[:, 192:]
        f16x8 wxf[3][2][4];
#pragma unroll
        for (int g = 0; g < 3; ++g)
#pragma unroll
            for (int j = 0; j < 2; ++j)
#pragma unroll
                for (int fi = 0; fi < 4; ++fi) {
                    const int row = g * 128 + (j ? c1 : c0);
                    const int k0 = fi * 32 + quad * 8;
                    wxf[g][j][fi] = cvt8(ld8(W_ih + row * 256 + (k0 < 64 ? k0 : 128 + k0)));
                }

        // projection weights (wave covers out cols pn)
        const int pn = pw * 16 + lm;
        const float bpv = bp[pn];
        f16x8 wPf[4];
#pragma unroll
        for (int fi = 0; fi < 4; ++fi)
            wPf[fi] = cvt8(ld8(Wp + pn * 128 + fi * 32 + quad * 8));

        auto prodLoad = [&](int gp, float4& px, float4& pm) {
            if (gp >= 24) { px = make_float4(0,0,0,0); pm = make_float4(0,0,0,0); return; }
            const int R = ptid >> 4, tg = 4 * gp + (R >> 2), b = R & 3;
            const size_t o = (((size_t)(b0 + b) * 96) + tg) * 64 + (ptid & 15) * 4;
            px = *(const float4*)(X + o);
            pm = *(const float4*)(mask + o);
        };
        auto prodStage = [&](int gp, float4 px, float4 pm) {
            const int R = ptid >> 4, toff = R >> 2, b = R & 3;
            const int tg = 4 * gp + toff, n0 = (ptid & 15) * 4;
            const float d = dt_lds[tg * 4 + b];
            const float xs[4] = {px.x, px.y, px.z, px.w};
            const float ms[4] = {pm.x, pm.y, pm.z, pm.w};
            f16x4 xi, mm;
#pragma unroll
            for (int e = 0; e < 4; ++e) {
                const int n = n0 + e;
                const float gxv = expnr_fast(d * wxl[n] + bxl[n]);
                const float muv = mu_l[b][n];
                float v;
                if (gp < 24) {  // LOCF collapse: m==0 -> X_locf == x_t
                    v = (ms[e] != 0.0f) ? xs[e] : (xs[e] - muv) * gxv + muv;
                    mm[e] = (_Float16)ms[e];
                } else {        // t>=96: x=0,m=0 -> x_in = (1-gx)*mu
                    v = (1.0f - gxv) * muv;
                    mm[e] = (_Float16)0.0f;
                }
                xi[e] = (_Float16)v;
            }
            *(f16x4*)&Astage[R * SR + n0]      = xi;
            *(f16x4*)&Astage[R * SR + 64 + n0] = mm;
        };
        auto prodMMA = [&](int gp, int j) {
            f16x8 ap[4];
#pragma unroll
            for (int fi = 0; fi < 4; ++fi)
                ap[fi] = *(const f16x8*)&Astage[lm * SR + fi * 32 + quad * 8];
            const int c = j ? c1 : c0;
            const int slot = (4 * gp + quad) & 7;  // lane's quad = time offset
            f32x4 aR = {0,0,0,0}, aZ = {0,0,0,0}, aN = {0,0,0,0};
#pragma unroll
            for (int fi = 0; fi < 4; ++fi) {
                aR = __builtin_amdgcn_mfma_f32_16x16x32_f16(ap[fi], wxf[0][j][fi], aR, 0, 0, 0);
                aZ = __builtin_amdgcn_mfma_f32_16x16x32_f16(ap[fi], wxf[1][j][fi], aZ, 0, 0, 0);
                aN = __builtin_amdgcn_mfma_f32_16x16x32_f16(ap[fi], wxf[2][j][fi], aN, 0, 0, 0);
            }
#pragma unroll
            for (int rb = 0; rb < 4; ++rb) {  // rb = batch (C/D reg)
                f16x4 pk = {(_Float16)aR[rb], (_Float16)aZ[rb], (_Float16)aN[rb], (_Float16)0.0f};
                *(f16x4*)&ring[slot * 2048 + c * 16 + rb * 4] = pk;
            }
        };

        __syncthreads();      // #1: mu/dt/wxl/V-zero visible
        {   // preamble: granule 0 (ring slots 0-3) — barrier between stage & MMA
            float4 px, pm;
            prodLoad(0, px, pm);
            prodStage(0, px, pm);
            barrier_lds_only();   // #2: Astage fully staged (cross-wave) BEFORE read
            prodMMA(0, 0); prodMMA(0, 1);
            barrier_lds_only();   // #3: granule 0 visible to consumers
        }

        float4 px, pm;
        for (int t = 0; t < 120; ++t) {
            const int gp = (t >> 2) + 1, ph = t & 3;
            if (ph == 0)      { if (gp < 30) prodLoad(gp, px, pm); }
            else if (ph == 1) { if (gp < 30) prodStage(gp, px, pm); }
            else if (ph == 2) { if (gp < 30) prodMMA(gp, 0); }
            else              { if (gp < 30) prodMMA(gp, 1); }

            if (t >= 96) {  // projection: rep_t = decayed h = V[t&1] tile
                f16x8 af[4];
#pragma unroll
                for (int fi = 0; fi < 4; ++fi)
                    af[fi] = *(const f16x8*)&V[t & 1][lm * SR + fi * 32 + quad * 8];
                f32x4 aP = {bpv, 0, 0, 0};
#pragma unroll
                for (int fi = 0; fi < 4; ++fi)
                    aP = __builtin_amdgcn_mfma_f32_16x16x32_f16(af[fi], wPf[fi], aP, 0, 0, 0);
                out[((size_t)(b0 + quad) * 24 + (t - 96)) * 64 + pn] = aP[0];
            }
            barrier_lds_only();
        }
    } else {
        // ===================== CONSUMER WAVES (0..7) =====================
        const int c = 16 * w + lm;  // this lane's single hidden col

        // h-part B-frags (W_ih cols 64..191; +W_hh folded for r,z): 64 VGPR
        f16x8 wR[4], wZ[4], wN[4], wG[4];
#pragma unroll
        for (int fi = 0; fi < 4; ++fi) {
            const int k0 = fi * 32 + quad * 8;
            wR[fi] = cvt8s(ld8(W_ih + c * 256 + 64 + k0),
                           ld8(W_hh + c * 128 + k0));
            wZ[fi] = cvt8s(ld8(W_ih + (128 + c) * 256 + 64 + k0),
                           ld8(W_hh + (128 + c) * 128 + k0));
            wN[fi] = cvt8(ld8(W_ih + (256 + c) * 256 + 64 + k0));
            wG[fi] = cvt8(ld8(W_hh + (256 + c) * 128 + k0));
        }
        float S = 0.0f;
        {
            const float4* wh4 = (const float4*)(Wh_dec + c * 64);
#pragma unroll
            for (int i = 0; i < 16; ++i) { float4 u = wh4[i]; S += u.x + u.y + u.z + u.w; }
        }
        const float bhc = bh_dec[c];
        const float bRc = b_ih[c] + b_hh[c];
        const float bZc = b_ih[128 + c] + b_hh[128 + c];
        const float bNc = b_ih[256 + c];
        const float bGc = b_hh[256 + c];

        __syncthreads();      // #1 (pairs with producer's)
        barrier_lds_only();   // #2 (volatile asm — cannot be merged)
        barrier_lds_only();   // #3

        const f32x4 ZV = {0.0f, 0.0f, 0.0f, 0.0f};
        float h = 0.0f;
        for (int t = 0; t < 120; ++t) {
            const _Float16* Vp = V[t & 1];
            const f16x4 g = *(const f16x4*)&ring[(t & 7) * 2048 + c * 16 + quad * 4];
            f16x8 af[4];
#pragma unroll
            for (int fi = 0; fi < 4; ++fi)
                af[fi] = *(const f16x8*)&Vp[lm * SR + fi * 32 + quad * 8];

            // gh for t+1, off the gate chain (clamped index; value unused at t=119)
            const int tn = (t < 119) ? t + 1 : 119;
            const float ghd = expnr_fast(dt_lds[tn * 4 + quad] * S + bhc);

            f32x4 aR = __builtin_amdgcn_mfma_f32_16x16x32_f16(af[0], wR[0], ZV, 0, 0, 0);
            f32x4 aZ = __builtin_amdgcn_mfma_f32_16x16x32_f16(af[0], wZ[0], ZV, 0, 0, 0);
            f32x4 aN = __builtin_amdgcn_mfma_f32_16x16x32_f16(af[0], wN[0], ZV, 0, 0, 0);
            f32x4 aG = __builtin_amdgcn_mfma_f32_16x16x32_f16(af[0], wG[0], ZV, 0, 0, 0);
#pragma unroll
            for (int fi = 1; fi < 4; ++fi) {
                aR = __builtin_amdgcn_mfma_f32_16x16x32_f16(af[fi], wR[fi], aR, 0, 0, 0);
                aZ = __builtin_amdgcn_mfma_f32_16x16x32_f16(af[fi], wZ[fi], aZ, 0, 0, 0);
                aN = __builtin_amdgcn_mfma_f32_16x16x32_f16(af[fi], wN[fi], aN, 0, 0, 0);
                aG = __builtin_amdgcn_mfma_f32_16x16x32_f16(af[fi], wG[fi], aG, 0, 0, 0);
            }

            // gate triple (C/D reg 0: tile row 4*quad = batch b0+quad)
            const float rg = sig_fast(aR[0] + ((float)g[0] + bRc));
            const float zg = sig_fast(aZ[0] + ((float)g[1] + bZc));
            const float ng = tanh_fast(aN[0] + ((float)g[2] + bNc) + rg * (aG[0] + bGc));
            h = (zg * (h - ng) + ng) * ghd;   // decayed h = rep_{t+1}
            if (t < 119)
                V[(t & 1) ^ 1][(4 * quad) * SR + c] = (_Float16)h;
            barrier_lds_only();
        }
    }
}

extern "C" void kernel_launch(void* const* d_in, const int* in_sizes, int n_in,
                              void* d_out, int out_size, void* d_ws, size_t ws_size,
                              hipStream_t stream) {
    const float* tp_pred = (const float*)d_in[0];
    const float* X       = (const float*)d_in[1];
    const float* tp_true = (const float*)d_in[2];
    const float* mask    = (const float*)d_in[3];
    const float* Wh_dec  = (const float*)d_in[4];
    const float* bh_dec  = (const float*)d_in[5];
    const float* Wx_dec  = (const float*)d_in[6];
    const float* bx_dec  = (const float*)d_in[7];
    const float* W_ih    = (const float*)d_in[8];
    const float* W_hh    = (const float*)d_in[9];
    const float* b_ih    = (const float*)d_in[10];
    const float* b_hh    = (const float*)d_in[11];
    const float* Wp      = (const float*)d_in[12];
    const float* bp      = (const float*)d_in[13];

    grud_kernel<<<dim3(256), dim3(768), 0, stream>>>(
        tp_pred, X, tp_true, mask, Wh_dec, bh_dec, Wx_dec, bx_dec,
        W_ih, W_hh, b_ih, b_hh, Wp, bp, (float*)d_out);
}